// Round 7
// baseline (2673.348 us; speedup 1.0000x reference)
//
#include <hip/hip_runtime.h>
#include <hip/hip_fp16.h>

#define B_ 32
#define T_ 4096
#define F_ 128
#define C_ 256
#define K_ 128
#define FC_ 384

typedef __attribute__((ext_vector_type(8))) short s8v;
typedef __attribute__((ext_vector_type(4))) float f4v;
typedef __attribute__((ext_vector_type(4))) int   i4v;

#define MFMA16(a,b,c) __builtin_amdgcn_mfma_f32_16x16x32_bf16((a),(b),(c),0,0,0)

#define LOG2E  1.442695041f
#define LOG2E2 2.885390082f
#define LN2    0.6931471806f

// ---- workspace layout (bytes) ----
#define WS_WSCAN 0u        // i8 scan weights, per-channel dword-packed: 512*64*4 = 131072
#define WS_SMAX  131072u   // 512 f32 per-column |w|max (g:0-255, a:256-511)
#define WS_W1F   262144u   // 12288 * 16 = 196608
#define WS_OWF   458752u   // 4096 * 16 = 65536
#define WS_BIAS1 524288u   // 768 * 4 = 3072
#define WS_CARRY 527360u   // n,d,h,am(scaled by log2e) : 4 * 8192 f32 = 131072
#define WS_DYN   658432u   // pre chunk (49152*Tc B) then hall chunk (16384*Tc B)

__device__ __forceinline__ unsigned short f2bf(float f){
  unsigned u = __float_as_uint(f);
  u += 0x7fffu + ((u>>16)&1u);     // round-to-nearest-even
  return (unsigned short)(u>>16);
}
__device__ __forceinline__ float h2f(unsigned short s){
  __half_raw r; r.x = s; return __half2float((__half)r);
}
__device__ __forceinline__ float fexp2(float x){
#if __has_builtin(__builtin_amdgcn_exp2f)
  return __builtin_amdgcn_exp2f(x);
#else
  return __expf(x*0.69314718056f);
#endif
}
__device__ __forceinline__ int dot4(int a, int b, int c){
#if __has_builtin(__builtin_amdgcn_sdot4)
  return __builtin_amdgcn_sdot4(a, b, c, false);
#else
  int r = c;
  r += (int)(char)(a      ) * (int)(char)(b      );
  r += (int)(char)(a >> 8 ) * (int)(char)(b >> 8 );
  r += (int)(char)(a >> 16) * (int)(char)(b >> 16);
  r += (int)(char)(a >> 24) * (int)(char)(b >> 24);
  return r;
#endif
}

// ---------------- per-column |w|max for i8 quant of scan weights ----------------
__global__ __launch_bounds__(256) void scale_kernel(
    const float* __restrict__ g_w, const float* __restrict__ a_w, char* __restrict__ ws)
{
  int id = blockIdx.x*256 + threadIdx.x;     // 512
  if (id >= 512) return;
  const float* src = (id < 256) ? g_w : a_w;
  int c = id & 255;
  float m = 0.0f;
  #pragma unroll 8
  for (int k=0;k<256;++k) m = fmaxf(m, fabsf(src[c*FC_ + F_ + k]));
  ((float*)(ws + WS_SMAX))[id] = fmaxf(m, 1e-30f);
}

// ---------------- weight packing ----------------
// scan weights: per-channel packed i8 dwords for v_dot4_i32_i8 GEMV.
// dword[(mat*256+c)*64 + kd], byte j = quant(W[c][F_+4kd+j]); mat 0=g, 1=a.
__global__ __launch_bounds__(256) void pack_kernel(
    const float* __restrict__ g_w, const float* __restrict__ u_w, const float* __restrict__ a_w,
    const float* __restrict__ g_b, const float* __restrict__ u_b, const float* __restrict__ o_w,
    char* __restrict__ ws)
{
  int id = blockIdx.x*256 + threadIdx.x;
  const float* smax = (const float*)(ws + WS_SMAX);
  unsigned short* w1f   = (unsigned short*)(ws + WS_W1F);
  unsigned short* owf   = (unsigned short*)(ws + WS_OWF);
  float* bias1          = (float*)(ws + WS_BIAS1);
  if (id < 8192){
    // thread id -> (mc = mat*256+c, i4); writes dwords kd = i4*4 .. i4*4+3
    int i4 = id & 15, mc = id >> 4;
    int c = mc & 255, mat = mc >> 8;
    const float* src = mat ? a_w : g_w;
    float inv = 127.0f / smax[mat*256 + c];
    int w32[4] = {0,0,0,0};
    #pragma unroll
    for (int j=0;j<16;++j){
      int k = i4*16 + j;
      int q8 = __float2int_rn(src[c*FC_ + F_ + k] * inv);
      w32[j>>2] |= (q8 & 0xff) << (8*(j&3));
    }
    int* dst = (int*)(ws + WS_WSCAN) + mc*64 + i4*4;
    dst[0]=w32[0]; dst[1]=w32[1]; dst[2]=w32[2]; dst[3]=w32[3];
  } else if (id < 8192+12288){
    // ph1 weights rows n: [0,256)=u_w, [256,512)=g_w x-part (*2log2e), [512,768)=a_w x-part (*log2e)
    int id2 = id - 8192;
    int l = id2 & 63, kc = (id2>>6)&3, nt = id2>>8;
    int n = nt*16 + (l&15);
    int kb = kc*32 + (l>>4)*8;
    float sc = (n < 256) ? 1.0f : (n < 512) ? LOG2E2 : LOG2E;
    #pragma unroll
    for (int j=0;j<8;++j){
      int k = kb + j;
      float v = (n < 256) ? u_w[n*F_ + k]
              : (n < 512) ? g_w[(n-256)*FC_ + k]
                          : a_w[(n-512)*FC_ + k];
      w1f[id2*8+j] = f2bf(v*sc);
    }
  } else if (id < 8192+12288+4096){
    int id3 = id - (8192+12288);
    int l = id3 & 63, kc = (id3>>6)&7, nt = id3>>9;
    int n = nt*16 + (l&15);
    int kb = kc*32 + (l>>4)*8;
    #pragma unroll
    for (int j=0;j<8;++j)
      owf[id3*8+j] = f2bf(o_w[n*C_ + kb + j]);
  } else if (id < 8192+12288+4096+768){
    int i = id - (8192+12288+4096);
    bias1[i] = (i<256) ? u_b[i] : (i<512 ? g_b[i-256]*LOG2E2 : 0.0f);
  }
}

// ---------------- init: carry <- initial state (a_max scaled by log2e) ----------------
__global__ __launch_bounds__(256) void init_kernel(
    const float* __restrict__ n0, const float* __restrict__ d0,
    const float* __restrict__ h0, const float* __restrict__ am0, char* __restrict__ ws)
{
  int id = blockIdx.x*256 + threadIdx.x;   // 8192
  float* c = (float*)(ws + WS_CARRY);
  c[id]        = n0[id];
  c[8192+id]   = d0[id];
  c[16384+id]  = h0[id];
  c[24576+id]  = am0[id]*LOG2E;
}

// ---------------- ph1: pre = x @ [u_w; g_w_x*2log2e; a_w_x*log2e]^T + bias (fp16) --------
__global__ __launch_bounds__(256) void ph1_kernel(const float* __restrict__ x, char* __restrict__ ws,
                                                  int t0, int Tc, int lgT16)
{
  const s8v* w1f = (const s8v*)(ws + WS_W1F);
  const float* bias1 = (const float*)(ws + WS_BIAS1);
  __half* pre = (__half*)(ws + WS_DYN);
  int tid = threadIdx.x;
  int wv = tid>>6, l = tid&63, q = l>>4, col = l&15;
  int wid = blockIdx.x*4 + wv;
  int b  = wid >> lgT16;
  int tb = (wid & ((1<<lgT16)-1))*16;
  s8v af[4];
  const float* xr = x + ((size_t)b*T_ + t0 + tb + col)*F_ + q*8;
  #pragma unroll
  for (int kc=0;kc<4;++kc){
    const float* p = xr + kc*32;
    float4 p0 = *(const float4*)(p);
    float4 p1 = *(const float4*)(p+4);
    s8v a;
    a[0]=(short)f2bf(p0.x); a[1]=(short)f2bf(p0.y); a[2]=(short)f2bf(p0.z); a[3]=(short)f2bf(p0.w);
    a[4]=(short)f2bf(p1.x); a[5]=(short)f2bf(p1.y); a[6]=(short)f2bf(p1.z); a[7]=(short)f2bf(p1.w);
    af[kc]=a;
  }
  for (int nt=0;nt<48;++nt){
    f4v acc = {0.f,0.f,0.f,0.f};
    #pragma unroll
    for (int kc=0;kc<4;++kc)
      acc = MFMA16(af[kc], w1f[(nt*4+kc)*64 + l], acc);
    int cg = nt*16 + col;
    float bs = bias1[cg];
    #pragma unroll
    for (int i=0;i<4;++i){
      int rl = tb + q*4 + i;
      pre[(size_t)(b*Tc + rl)*768 + cg] = __float2half(acc[i] + bs);
    }
  }
}

// ---------------- scan: sequential recurrence, 1 batch row per block ----------------
// R7: dot4 GEMV with BOTH root causes of R1-R6's weight refetch removed:
//  (a) rule-#20 scratch: all 128 weight dwords are NAMED SCALARS (no arrays, no
//      runtime-indexed allocas) loaded once pre-loop;
//  (b) the per-step asm "memory" clobber (which forbade caching memory loads across
//      iterations) is GONE: all in-loop LDS ops are volatile inline asm (mutually
//      ordered), with the lgkmcnt(0) inside the same asm block as its ds ops, so
//      no compiler memory fence is needed at all.
// Each lane owns channel c=tid: 128 sdot4/step in 8 chains, no accumulator selects.
#define DG(H,I) ag0=dot4(H[0],wg##I##_0,ag0); ag1=dot4(H[1],wg##I##_1,ag1); \
                ag2=dot4(H[2],wg##I##_2,ag2); ag3=dot4(H[3],wg##I##_3,ag3);
#define DA(H,I) aa0=dot4(H[0],wa##I##_0,aa0); aa1=dot4(H[1],wa##I##_1,aa1); \
                aa2=dot4(H[2],wa##I##_2,aa2); aa3=dot4(H[3],wa##I##_3,aa3);
#define WLD(I) \
  int wg##I##_0,wg##I##_1,wg##I##_2,wg##I##_3, wa##I##_0,wa##I##_1,wa##I##_2,wa##I##_3; \
  { i4v t_ = wp4[(size_t)c*16 + I];       wg##I##_0=t_[0]; wg##I##_1=t_[1]; wg##I##_2=t_[2]; wg##I##_3=t_[3]; } \
  { i4v t_ = wp4[(size_t)(256+c)*16 + I]; wa##I##_0=t_[0]; wa##I##_1=t_[1]; wa##I##_2=t_[2]; wa##I##_3=t_[3]; }

#define RD8(A0,A1,A2,A3,A4,A5,A6,A7,RA,O0,O1,O2,O3,O4,O5,O6,O7) \
  asm volatile( \
    "ds_read_b128 %0, %8 offset:" #O0 "\n\t" \
    "ds_read_b128 %1, %8 offset:" #O1 "\n\t" \
    "ds_read_b128 %2, %8 offset:" #O2 "\n\t" \
    "ds_read_b128 %3, %8 offset:" #O3 "\n\t" \
    "ds_read_b128 %4, %8 offset:" #O4 "\n\t" \
    "ds_read_b128 %5, %8 offset:" #O5 "\n\t" \
    "ds_read_b128 %6, %8 offset:" #O6 "\n\t" \
    "ds_read_b128 %7, %8 offset:" #O7 "\n\t" \
    "s_waitcnt lgkmcnt(0)" \
    : "=&v"(A0),"=&v"(A1),"=&v"(A2),"=&v"(A3),"=&v"(A4),"=&v"(A5),"=&v"(A6),"=&v"(A7) \
    : "v"(RA))

#define STEP(PH, S) do { \
  const unsigned ra_ = hb + (unsigned)((PH&1)*256); \
  const unsigned wa_ = hb + (unsigned)((((PH&1)^1)*256) + c); \
  float fu = h2f(su##PH), fg = h2f(sg##PH), fa = h2f(sa##PH); \
  { int nxt_ = ((S)+4 < Tc) ? (S)+4 : (S); size_t o_ = prb + (size_t)nxt_*768; \
    su##PH = prbu[o_ + c]; sg##PH = prbu[o_ + 256 + c]; sa##PH = prbu[o_ + 512 + c]; } \
  int ag0=0,ag1=0,ag2=0,ag3=0, aa0=0,aa1=0,aa2=0,aa3=0; \
  { i4v h0,h1,h2,h3,h4,h5,h6,h7; \
    RD8(h0,h1,h2,h3,h4,h5,h6,h7, ra_, 0,16,32,48,64,80,96,112); \
    DG(h0,0) DA(h0,0) DG(h1,1) DA(h1,1) DG(h2,2) DA(h2,2) DG(h3,3) DA(h3,3) \
    DG(h4,4) DA(h4,4) DG(h5,5) DA(h5,5) DG(h6,6) DA(h6,6) DG(h7,7) DA(h7,7) } \
  { i4v k0,k1,k2,k3,k4,k5,k6,k7; \
    RD8(k0,k1,k2,k3,k4,k5,k6,k7, ra_, 128,144,160,176,192,208,224,240); \
    DG(k0,8) DA(k0,8) DG(k1,9) DA(k1,9) DG(k2,10) DA(k2,10) DG(k3,11) DA(k3,11) \
    DG(k4,12) DA(k4,12) DG(k5,13) DA(k5,13) DG(k6,14) DA(k6,14) DG(k7,15) DA(k7,15) } \
  float g = (float)((ag0+ag1)+(ag2+ag3)) * gsc + fg;     /* = 2log2e * g_raw */ \
  float a = (float)((aa0+aa1)+(aa2+aa3)) * asc + fa;     /* = log2e * a_raw */ \
  float z = fu * (1.0f - 2.0f*__builtin_amdgcn_rcpf(fexp2(g) + 1.0f)); \
  float anew = fmaxf(cm,a); \
  float dmin = fminf(cm,a); \
  float e = fexp2(dmin-anew); \
  bool ge = (a>=cm); \
  float ed = ge? e : 1.0f; \
  float es = ge? 1.0f : e; \
  cn = cn*ed + z*es; \
  cd = fmaf(cd,ed,es); \
  float hv = 1.0f - 2.0f*__builtin_amdgcn_rcpf(fexp2(LOG2E2*(cn*__builtin_amdgcn_rcpf(cd))) + 1.0f); \
  cm = anew; \
  hrow[(size_t)(S)*C_] = f2bf(hv); \
  int hq_ = (int)(char)__float2int_rn(hv*127.0f); \
  asm volatile("ds_write_b8 %0, %1\n\t" \
               "s_waitcnt lgkmcnt(0)\n\t" \
               "s_barrier" :: "v"(wa_), "v"(hq_)); \
} while(0)

__global__ __launch_bounds__(256,1) void scan_kernel(char* __restrict__ ws, int Tc)
{
  __shared__ __align__(16) char h8buf[2][256];
  const i4v* wp4 = (const i4v*)(ws + WS_WSCAN);
  const float* smax = (const float*)(ws + WS_SMAX);
  const unsigned short* prbu = (const unsigned short*)(ws + WS_DYN);
  unsigned short* hall = (unsigned short*)(ws + WS_DYN + 49152u*(unsigned)Tc);
  float* carry = (float*)(ws + WS_CARRY);
  int c = threadIdx.x;                 // this lane's channel (0..255)
  int b = blockIdx.x;

  // one-time weight load into 256 NAMED scalar dwords (no arrays -> no scratch)
  WLD(0) WLD(1) WLD(2) WLD(3) WLD(4) WLD(5) WLD(6) WLD(7)
  WLD(8) WLD(9) WLD(10) WLD(11) WLD(12) WLD(13) WLD(14) WLD(15)

  float gsc = smax[c]     * (LOG2E2/16129.0f);   // maxg/(127*127) * 2log2e
  float asc = smax[256+c] * (LOG2E /16129.0f);

  int gi = b*C_ + c;
  float cn = carry[gi], cd = carry[8192+gi], cm = carry[24576+gi];
  h8buf[0][c] = (char)__float2int_rn(carry[16384+gi]*127.0f);
  __syncthreads();

  unsigned hb = (unsigned)(unsigned long long)(void*)&h8buf[0][0];
  const size_t prb = (size_t)b*Tc*768;
  unsigned short* hrow = hall + (size_t)b*Tc*C_ + c;

  // prefetch pre for t=0..3 (named slots; 4-deep pipeline, no vm drains in loop)
  unsigned short su0,su1,su2,su3, sg0,sg1,sg2,sg3, sa0,sa1,sa2,sa3;
  su0=prbu[prb+c];        sg0=prbu[prb+256+c];        sa0=prbu[prb+512+c];
  su1=prbu[prb+768+c];    sg1=prbu[prb+768+256+c];    sa1=prbu[prb+768+512+c];
  su2=prbu[prb+1536+c];   sg2=prbu[prb+1536+256+c];   sa2=prbu[prb+1536+512+c];
  su3=prbu[prb+2304+c];   sg3=prbu[prb+2304+256+c];   sa3=prbu[prb+2304+512+c];

  #pragma unroll 1
  for (int t=0;t<Tc;t+=4){
    STEP(0, t+0);
    STEP(1, t+1);
    STEP(2, t+2);
    STEP(3, t+3);
  }
  // write back carry
  carry[gi] = cn; carry[8192+gi] = cd; carry[24576+gi] = cm;
  carry[16384+gi] = 1.0f - 2.0f*__builtin_amdgcn_rcpf(fexp2(LOG2E2*(cn*__builtin_amdgcn_rcpf(cd))) + 1.0f);
}

// ---------------- ph3: outs = h @ o_w^T + o_b ----------------
__global__ __launch_bounds__(256) void ph3_kernel(const float* __restrict__ o_b,
                                                  char* __restrict__ ws, float* __restrict__ out,
                                                  int t0, int Tc, int lgT16)
{
  const s8v* owf = (const s8v*)(ws + WS_OWF);
  const unsigned short* hall = (const unsigned short*)(ws + WS_DYN + 49152u*(unsigned)Tc);
  int tid = threadIdx.x;
  int wv = tid>>6, l = tid&63, q=l>>4, col=l&15;
  int wid = blockIdx.x*4 + wv;
  int bb = wid >> lgT16;
  int tt = (wid & ((1<<lgT16)-1))*16;
  const unsigned short* src = hall + ((size_t)bb*Tc + tt)*C_;
  s8v af[8];
  #pragma unroll
  for (int kc=0;kc<8;++kc)
    af[kc] = *(const s8v*)(src + (size_t)col*C_ + kc*32 + q*8);
  #pragma unroll
  for (int nt=0;nt<8;++nt){
    f4v acc={0.f,0.f,0.f,0.f};
    #pragma unroll
    for (int kc=0;kc<8;++kc)
      acc = MFMA16(af[kc], owf[(nt*8+kc)*64 + l], acc);
    int k = nt*16+col;
    float bs = o_b[k];
    #pragma unroll
    for (int i=0;i<4;++i)
      out[((size_t)bb*T_ + t0 + tt + q*4 + i)*K_ + k] = acc[i] + bs;
  }
}

// ---------------- finalize: final states -> out tail (unscale a_max) ----------------
__global__ __launch_bounds__(256) void fin_kernel(char* __restrict__ ws, float* __restrict__ out)
{
  int id = blockIdx.x*256 + threadIdx.x;   // 8192
  const float* c = (const float*)(ws + WS_CARRY);
  size_t ob = (size_t)B_*T_*K_;
  out[ob + id]         = c[id];            // n_t
  out[ob + 8192 + id]  = c[8192+id];       // d_t
  out[ob + 16384 + id] = c[16384+id];      // h_t
  out[ob + 24576 + id] = c[24576+id]*LN2;  // a_new (unscale)
}

extern "C" void kernel_launch(void* const* d_in, const int* in_sizes, int n_in,
                              void* d_out, int out_size, void* d_ws, size_t ws_size,
                              hipStream_t stream)
{
  const float* x   = (const float*)d_in[0];
  const float* n0  = (const float*)d_in[1];
  const float* d0  = (const float*)d_in[2];
  const float* h0  = (const float*)d_in[3];
  const float* am0 = (const float*)d_in[4];
  const float* g_w = (const float*)d_in[5];
  const float* g_b = (const float*)d_in[6];
  const float* u_w = (const float*)d_in[7];
  const float* u_b = (const float*)d_in[8];
  const float* a_w = (const float*)d_in[9];
  const float* o_w = (const float*)d_in[10];
  const float* o_b = (const float*)d_in[11];
  float* out = (float*)d_out;
  char* ws = (char*)d_ws;

  unsigned Tc = 4096;
  while (Tc > 64 && (size_t)WS_DYN + 65536ull*Tc > ws_size) Tc >>= 1;
  if ((size_t)WS_DYN + 65536ull*Tc > ws_size) return;
  int lgTc  = __builtin_ctz(Tc);
  int lgT16 = lgTc - 4;
  int nch   = T_ / (int)Tc;

  hipLaunchKernelGGL(scale_kernel, dim3(2), dim3(256), 0, stream, g_w, a_w, ws);
  hipLaunchKernelGGL(pack_kernel, dim3(99), dim3(256), 0, stream,
                     g_w, u_w, a_w, g_b, u_b, o_w, ws);
  hipLaunchKernelGGL(init_kernel, dim3(32), dim3(256), 0, stream,
                     n0, d0, h0, am0, ws);
  for (int c0=0; c0<nch; ++c0){
    int t0 = c0*(int)Tc;
    hipLaunchKernelGGL(ph1_kernel, dim3(B_*(int)Tc/64), dim3(256), 0, stream,
                       x, ws, t0, (int)Tc, lgT16);
    hipLaunchKernelGGL(scan_kernel, dim3(B_), dim3(256), 0, stream,
                       ws, (int)Tc);
    hipLaunchKernelGGL(ph3_kernel, dim3(B_*(int)Tc/64), dim3(256), 0, stream,
                       o_b, ws, out, t0, (int)Tc, lgT16);
  }
  hipLaunchKernelGGL(fin_kernel, dim3(32), dim3(256), 0, stream, ws, out);
}